// Round 4
// baseline (249.704 us; speedup 1.0000x reference)
//
#include <hip/hip_runtime.h>

// LabelLoss: out[b] = sum_{n,c<7} (pred[b,n,c] - gt[b,n,c])^2
// pred/gt: [256, 16384, 8] fp32.
//
// History:
//  R1-R4: ~100 us (2.7 TB/s) allocating loads, structure-invariant.
//  R6-R7: nt vector loads (L1 bypass) + dbuf pipeline -> ~75 us (3.6 TB/s).
//  R8:    inline-asm VGPR-dest loads w/ manual vmcnt -> core dump. Never
//         hand-roll untracked VGPR-destination loads.
//  R9:    buffer_load sc0 sc1 nt (L1+L2 bypass) -> NULL (252 us).
//  R10:   LDS-DMA (global_load_lds, nt) -> NULL (249.6 us). Three distinct
//         read paths all saturate at ~3.6 TB/s read.
//  R11 (this): decisive experiment between
//         H1 "per-path service cap (~14 GB/s/CU each)" and
//         H2 "chip-level read-stream ceiling (~3.6 TB/s, cf. m13 copy
//            = 3.15 TB/s read + 3.15 TB/s write)".
//         Drive BOTH paths CONCURRENTLY: pred via nt vector loads (VGPR
//         return), gt via global_load_lds (LDS FIFO), interleaved per
//         chunk, counted vmcnt(4) (2 ops/chunk, 2 chunks in flight, never
//         0 in-loop), 4-buffer LDS rotation, thread-private slots (no
//         barriers), full unroll so all indices are compile-time.
//         H1 -> kernel ~50 us (dur ~225). H2 -> null -> declare roofline.

#define THREADS 256
#define SPLIT 8                               // blocks per batch row
#define F4_PER_BATCH (16384 * 2)              // 32768 float4s per batch per input
#define F4_PER_BLOCK (F4_PER_BATCH / SPLIT)   // 4096
#define NCHUNK (F4_PER_BLOCK / THREADS)       // 16 chunks per block
#define NBUF 4                                // LDS buffer rotation depth

typedef float vfloat4 __attribute__((ext_vector_type(4)));

__global__ __launch_bounds__(THREADS) void label_loss_kernel(
    const vfloat4* __restrict__ pred,
    const vfloat4* __restrict__ gt,
    float* __restrict__ out)
{
    // 4 rotating gt buffers: 4*256*16B = 16 KiB -> 8 blocks/CU (<=160K).
    __shared__ vfloat4 lbuf[NBUF][THREADS];

    const int tid  = (int)threadIdx.x;
    const int wave = tid >> 6;                // DMA dest: wave base + lane*16
    const int b    = blockIdx.x / SPLIT;
    const int seg  = blockIdx.x % SPLIT;
    const int base_f4 = b * F4_PER_BATCH + seg * F4_PER_BLOCK + tid;

    // Channel-7 mask: float4 index parity == tid&1 (all strides even):
    // lane-uniform, no divergence.
    const float m = (tid & 1) ? 0.0f : 1.0f;

// Direct global->LDS DMA, 16B per lane, nt policy (aux=2). Lane l of the
// wave lands at base + l*16 -> slot (wave*64+l) == tid. Thread-private.
#define GLD_LDS(gp_, lp_)                                                   \
    __builtin_amdgcn_global_load_lds(                                       \
        (const __attribute__((address_space(1))) unsigned*)(gp_),           \
        (__attribute__((address_space(3))) unsigned*)(lp_), 16, 0, 2)

    vfloat4 P[NBUF];          // rotating pred regs (all indices static
                              // after full unroll -> stays in VGPRs)
    float acc = 0.0f;

// One chunk = 2 vmcnt ops: [vector nt load of pred] + [LDS-DMA of gt].
#define ISSUE(c_) do {                                                      \
    const int g_ = base_f4 + (c_) * THREADS;                                \
    P[(c_) & (NBUF - 1)] = __builtin_nontemporal_load(&pred[g_]);           \
    GLD_LDS(&gt[g_], &lbuf[(c_) & (NBUF - 1)][wave << 6]);                  \
  } while (0)

// Counted wait; sched_barrier stops the consume from hoisting above it
// (rule #18: "memory" clobber does not order register-only consumers).
#define WAITN(n_) do {                                                      \
    asm volatile("s_waitcnt vmcnt(" #n_ ")" ::: "memory");                  \
    __builtin_amdgcn_sched_barrier(0);                                      \
  } while (0)

#define CONSUME(c_) do {                                                    \
    const vfloat4 d_ = P[(c_) & (NBUF - 1)] - lbuf[(c_) & (NBUF - 1)][tid]; \
    acc += d_.x * d_.x + d_.y * d_.y + d_.z * d_.z + m * (d_.w * d_.w);     \
  } while (0)

    // Prologue: 2 chunks in flight (4 ops).
    ISSUE(0);
    ISSUE(1);

    // Steady state: issue chunk c+2 (6 ops outstanding worst case), wait
    // down to 4 (chunk c's pair landed; c+1/c+2 still in flight), consume.
    // Buffer (c+2)&3 differs from (c)&3 and (c+1)&3; its previous tenant
    // (chunk c-2) was ds_read two iterations ago behind a sched_barrier,
    // and the DMA's LDS write lands >=HBM-latency after issue -> no race.
    #pragma unroll
    for (int c = 0; c < NCHUNK; ++c) {
        if (c + 2 < NCHUNK)      { ISSUE(c + 2); WAITN(4); }
        else if (c + 1 < NCHUNK) { WAITN(2); }
        else                     { WAITN(0); }
        CONSUME(c);
    }

#undef ISSUE
#undef WAITN
#undef CONSUME
#undef GLD_LDS

    float v = acc;

    // 64-lane wave reduction
    #pragma unroll
    for (int off = 32; off > 0; off >>= 1)
        v += __shfl_down(v, off, 64);

    __shared__ float wsum[THREADS / 64];
    const int lane = tid & 63;
    if (lane == 0) wsum[wave] = v;
    __syncthreads();

    if (tid == 0) {
        atomicAdd(&out[b], wsum[0] + wsum[1] + wsum[2] + wsum[3]);
    }
}

extern "C" void kernel_launch(void* const* d_in, const int* in_sizes, int n_in,
                              void* d_out, int out_size, void* d_ws, size_t ws_size,
                              hipStream_t stream) {
    const vfloat4* pred = (const vfloat4*)d_in[0];
    const vfloat4* gt   = (const vfloat4*)d_in[1];
    float* out = (float*)d_out;

    // d_out is re-poisoned to 0xAA before every launch; we accumulate with
    // atomics, so zero it first (async memset is graph-capture safe).
    (void)hipMemsetAsync(d_out, 0, (size_t)out_size * sizeof(float), stream);

    const int n_blocks = 256 * SPLIT;  // 2048 blocks, 8 per CU
    label_loss_kernel<<<dim3(n_blocks), dim3(THREADS), 0, stream>>>(pred, gt, out);
}